// Round 14
// baseline (48.723 us; speedup 1.0000x reference)
//
#include <hip/hip_runtime.h>

// TemporalContrastiveLoss: B=512, T=256, D=256, temperature 0.1.
// Grid = 256 blocks (1/CU), 1024 threads (16 waves, forced 4/SIMD),
// 2 batches sequential per block. MINIMAL-BARRIER structure (~5/batch):
//   stage full X[b] fp32->bf16 into swizzled LDS (128 KiB, one pass) ->
//   barrier -> each wave: one 64x64 tile, K=256, BARRIER-FREE 16-iter loop
//   (4 ds_read_b128 + 4 MFMA; compiler software-pipelines with counted
//   lgkmcnt) -> diag waves publish inv=rsqrt(diag) -> barrier ->
//   register-local symmetric column-sum LSE epilogue (fixed max=10) +
//   super-diag target -> barrier -> merge -> partial. K3: 512->1 mean.
// Rationale: occupancy (r13), vmcnt-drain (r7), prefetch depth (r9) all
// nulled; remaining binder is barrier-lockstep phases. Waves free-run here.

typedef float f32x4  __attribute__((ext_vector_type(4)));
typedef float f32x16 __attribute__((ext_vector_type(16)));
typedef unsigned int u32x2 __attribute__((ext_vector_type(2)));
typedef unsigned int u32x4 __attribute__((ext_vector_type(4)));
typedef __bf16 bf16x8 __attribute__((ext_vector_type(8)));

#define NB 512
#define NT 256
#define ND 256
#define K10L2E 14.42695041f   // 10 * log2(e)

#define MFMA32 __builtin_amdgcn_mfma_f32_32x32x16_bf16

__device__ __forceinline__ unsigned int f2bf_rne(float f) {
  unsigned int u = __float_as_uint(f);
  return (u + 0x7fffu + ((u >> 16) & 1u)) >> 16;
}

// LDS layout (round-5 proven): [256 rows][32 chunks of 16B],
// chunk slot = c ^ (row&7)  (byte ^= (row&7)<<4) -> conflict-free
// ds_read_b128 frag reads and 2-way-free ds_write_b64 staging.
__global__ __launch_bounds__(1024, 4) void fused_kernel(
    const float* __restrict__ x, float* __restrict__ partial) {
  __shared__ u32x4 X[NT * 32];       // 128 KiB bf16 matrix (swizzled)
  __shared__ float invbuf[NT];       // 1/||x_r|| from MFMA diagonal
  __shared__ float sbuf[NT][5];      // per-col, per-64row-group sum exp(p-10)
  __shared__ float tbuf[NT];         // per-row target logit (x10, normalized)
  __shared__ float redbuf[16];

  const int t    = threadIdx.x;
  const int wave = t >> 6;
  const int lane = t & 63;
  const int lo5  = lane & 31;
  const int hi   = lane >> 5;
  const int sx6  = lo5 & 6;
  const int hx   = hi ^ (lo5 & 1);

  // one 64x64 tile per wave
  const int tr = wave >> 2;
  const int tc = wave & 3;
  const int R = tr * 64, C = tc * 64;
  const int iA0 = (R + lo5) * 32;
  const int iA1 = (R + 32 + lo5) * 32;
  const int iB0 = (C + lo5) * 32;
  const int iB1 = (C + 32 + lo5) * 32;

#pragma unroll 1
  for (int b = 0; b < 2; ++b) {
    const float* xb = x + ((size_t)blockIdx.x + (size_t)b * 256) * (NT * ND);

    // ---- phase 1: stage full X[b], fp32 -> bf16, swizzled -------------
    // wave stages rows wave*16 .. +15; each row: 64 lanes x f32x4 (1 KiB).
    {
      f32x4 ld[16];
#pragma unroll
      for (int i = 0; i < 16; ++i)
        ld[i] = *(const f32x4*)(xb + (wave * 16 + i) * ND + lane * 4);
#pragma unroll
      for (int i = 0; i < 16; ++i) {
        const int r = wave * 16 + i;
        u32x2 o;
        o.x = f2bf_rne(ld[i].x) | (f2bf_rne(ld[i].y) << 16);
        o.y = f2bf_rne(ld[i].z) | (f2bf_rne(ld[i].w) << 16);
        const int slot = (lane >> 1) ^ (r & 7);
        *(u32x2*)((unsigned int*)X + (r * 128 + slot * 4 + (lane & 1) * 2)) = o;
      }
    }
    __syncthreads();

    // ---- phase 2: barrier-free GEMM, one tile, K=256 ------------------
    f32x16 a0, a1, a2, a3;
#pragma unroll
    for (int e = 0; e < 16; ++e) { a0[e] = 0.f; a1[e] = 0.f; a2[e] = 0.f; a3[e] = 0.f; }

#pragma unroll 4
    for (int kb = 0; kb < 16; ++kb) {
      const int ko = ((kb * 2) ^ sx6) | hx;
      bf16x8 fa0 = __builtin_bit_cast(bf16x8, X[iA0 + ko]);
      bf16x8 fa1 = __builtin_bit_cast(bf16x8, X[iA1 + ko]);
      bf16x8 fb0 = __builtin_bit_cast(bf16x8, X[iB0 + ko]);
      bf16x8 fb1 = __builtin_bit_cast(bf16x8, X[iB1 + ko]);
      a0 = MFMA32(fa0, fb0, a0, 0, 0, 0);
      a1 = MFMA32(fa0, fb1, a1, 0, 0, 0);
      a2 = MFMA32(fa1, fb0, a2, 0, 0, 0);
      a3 = MFMA32(fa1, fb1, a3, 0, 0, 0);
    }

    // diag waves publish inv = rsqrt(diag)
    if (tr == tc) {
      float dv0 = 1.0f, dv1 = 1.0f;
#pragma unroll
      for (int rg = 0; rg < 16; ++rg) {
        const int rowe = (rg & 3) + 8 * (rg >> 2) + 4 * hi;
        if (rowe == lo5) { dv0 = a0[rg]; dv1 = a3[rg]; }
      }
      if (hi == ((lo5 >> 2) & 1)) {
        invbuf[R + lo5]      = rsqrtf(fmaxf(dv0, 1e-24f));
        invbuf[R + 32 + lo5] = rsqrtf(fmaxf(dv1, 1e-24f));
      }
    }
    __syncthreads();   // invbuf valid

    // ---- phase 3: register-local epilogue -----------------------------
    // scaled exp column-sums (S symmetric: row-LSE sum == column sum)
    {
      const float ic0 = invbuf[C + lo5] * K10L2E;
      const float ic1 = invbuf[C + 32 + lo5] * K10L2E;
      float e0 = 0.f, e1 = 0.f;
#pragma unroll
      for (int rg = 0; rg < 16; ++rg) {
        const int rowe = (rg & 3) + 8 * (rg >> 2) + 4 * hi;
        const float ir0 = invbuf[R + rowe], ir1 = invbuf[R + 32 + rowe];
        e0 += exp2f(fmaf(a0[rg] * ir0, ic0, -K10L2E));
        e0 += exp2f(fmaf(a2[rg] * ir1, ic0, -K10L2E));
        e1 += exp2f(fmaf(a1[rg] * ir0, ic1, -K10L2E));
        e1 += exp2f(fmaf(a3[rg] * ir1, ic1, -K10L2E));
      }
      e0 += __shfl_xor(e0, 32);
      e1 += __shfl_xor(e1, 32);
      if (hi == 0) sbuf[C + lo5][tr] = e0;
      else         sbuf[C + 32 + lo5][tr] = e1;
    }

    // super-diagonal target (tiles with tc==tr or tc==tr+1)
    if (tc == tr || tc == tr + 1) {
#pragma unroll
      for (int ar = 0; ar < 2; ++ar) {
#pragma unroll
        for (int rg = 0; rg < 16; ++rg) {
          const int r = R + ar * 32 + (rg & 3) + 8 * (rg >> 2) + 4 * hi;
          const int tcol = r + 1 - C;
          if (r < NT - 1 && tcol >= 0 && tcol < 64 && lo5 == (tcol & 31)) {
            const float v = (tcol < 32) ? (ar ? a2[rg] : a0[rg])
                                        : (ar ? a3[rg] : a1[rg]);
            tbuf[r] = 10.0f * v * invbuf[r] * invbuf[r + 1];
          }
        }
      }
    }
    __syncthreads();   // sbuf/tbuf complete

    // ---- merge 4 row-groups per column, subtract target, reduce -------
    float val = 0.0f;
    if (t < NT - 1) {
      const float s = sbuf[t][0] + sbuf[t][1] + sbuf[t][2] + sbuf[t][3];
      val = 10.0f + __logf(s) - tbuf[t];
    }
#pragma unroll
    for (int dd = 1; dd < 64; dd <<= 1) val += __shfl_xor(val, dd);
    if (lane == 0) redbuf[wave] = val;
    __syncthreads();
    if (t == 0) {
      float s = 0.f;
#pragma unroll
      for (int w = 0; w < 16; ++w) s += redbuf[w];
      partial[blockIdx.x + b * 256] = s;
    }
    __syncthreads();   // X / redbuf reusable for next batch
  }
}

// ---------------- K3: 512 partials -> mean (deterministic) ----------------
__global__ __launch_bounds__(256) void reduce_kernel(
    const float* __restrict__ partial, float* __restrict__ out) {
  const int t = threadIdx.x;
  float v = partial[t] + partial[t + 256];
#pragma unroll
  for (int d = 1; d < 64; d <<= 1) v += __shfl_xor(v, d);
  __shared__ float red[4];
  if ((t & 63) == 0) red[t >> 6] = v;
  __syncthreads();
  if (t == 0)
    out[0] = (red[0] + red[1] + red[2] + red[3]) * (1.0f / (float)(NB * (NT - 1)));
}

extern "C" void kernel_launch(void* const* d_in, const int* in_sizes, int n_in,
                              void* d_out, int out_size, void* d_ws, size_t ws_size,
                              hipStream_t stream) {
  (void)in_sizes; (void)n_in; (void)out_size; (void)ws_size;
  const float* x = (const float*)d_in[0];
  float* out = (float*)d_out;
  float* partial = (float*)d_ws;   // 2 KiB

  hipLaunchKernelGGL(fused_kernel, dim3(NB / 2), dim3(1024), 0, stream, x, partial);
  hipLaunchKernelGGL(reduce_kernel, dim3(1), dim3(256), 0, stream, partial, out);
}

// Round 16
// 45.658 us; speedup vs baseline: 1.0671x; 1.0671x over previous
//
#include <hip/hip_runtime.h>

// TemporalContrastiveLoss: B=512, T=256, D=256, temperature 0.1.
// Grid = 256 blocks (1/CU, 512 thr, launch_bounds(512,2)). 2 batches/block.
// S_raw = X*X^T over 16 sub-chunks (32 cols, 2 batches x 8), depth-2
// register prefetch (ldA[4]/ldB[4], 32 VGPR -- proven no-spill, r9=38.7us).
// lgkm-only barriers (vmcnt never drained in-loop). Symmetric column-sum
// LSE (fixed max=10), super-diagonal target.
// Single-dispatch: last block (device-scope atomic counter, zeroed per
// launch via hipMemsetAsync) reduces the 512 partials in fixed order and
// writes the mean (bitwise-deterministic across replays).
// r15 bugfix: final reduce guarded to t<256 (512-thread block was
// double-counting partial[256..511] and reading OOB).

typedef float f32x4  __attribute__((ext_vector_type(4)));
typedef float f32x16 __attribute__((ext_vector_type(16)));
typedef unsigned int u32x2 __attribute__((ext_vector_type(2)));
typedef unsigned int u32x4 __attribute__((ext_vector_type(4)));
typedef __bf16 bf16x8 __attribute__((ext_vector_type(8)));

#define NB 512
#define NT 256
#define ND 256
#define K10L2E 14.42695041f   // 10 * log2(e)

#define MFMA32 __builtin_amdgcn_mfma_f32_32x32x16_bf16

__device__ __forceinline__ unsigned int f2bf_rne(float f) {
  unsigned int u = __float_as_uint(f);
  return (u + 0x7fffu + ((u >> 16) & 1u)) >> 16;
}

// Barrier that does NOT drain vmcnt (prefetch stays in flight).
__device__ __forceinline__ void wg_barrier() {
  asm volatile("s_waitcnt lgkmcnt(0)" ::: "memory");
  __builtin_amdgcn_s_barrier();
  asm volatile("" ::: "memory");
}

__device__ __forceinline__ u32x2 pack_bf16x4(f32x4 v) {
  u32x2 o;
  o.x = f2bf_rne(v.x) | (f2bf_rne(v.y) << 16);
  o.y = f2bf_rne(v.z) | (f2bf_rne(v.w) << 16);
  return o;
}

// LDS sub-chunk layout (32 cols, 16 KiB): [128 double-rows][8 slot16 of 16B],
// row r, logical 8-col slot s: slot16 = ((r&1)*4 + s) ^ ((r>>1)&7)
// -> ds_read_b128 frags and ds_write_b64 staging both <=2-way (free).
__global__ __launch_bounds__(512, 2) void fused_kernel(
    const float* __restrict__ x, float* __restrict__ partial,
    unsigned int* __restrict__ counter, float* __restrict__ out) {
  __shared__ u32x4 ck[2][128 * 8];   // 2 x 16 KiB sub-chunk double buffer
  __shared__ float invbuf[NT];       // 1/||x_r|| from MFMA diagonal
  __shared__ float sbuf[NT][5];      // per-col, per-64row-group sum exp(p-10)
  __shared__ float tbuf[NT];         // per-row target logit (x10, normalized)
  __shared__ float redbuf[8];
  __shared__ unsigned int doneflag;

  const int t    = threadIdx.x;
  const int wave = t >> 6;
  const int lane = t & 63;
  const int lo5  = lane & 31;
  const int hi   = lane >> 5;
  const int sxd  = (lo5 >> 1) & 7;   // frag-read row-derived xor
  const int sx4  = (lo5 & 1) * 4;

  // tile assignment: wave w -> tiles (tr, tcA), (tr, tcB); w<4 has diag in A
  const int d   = wave >> 2;
  const int tr  = wave & 3;
  const int tcA = (tr + d) & 3;
  const int tcB = (tr + d + 2) & 3;
  const int R = tr * 64, CA = tcA * 64, CB = tcB * 64;

  // frag base indices (u32x4 units): rows group+lo5; +32 rows => +128
  const int iA  = ((R  + lo5) >> 1) * 8;
  const int iBA = ((CA + lo5) >> 1) * 8;
  const int iBB = ((CB + lo5) >> 1) * 8;

  // staging: wave stages rows wave*32..+31 of each 32-col sub-chunk
  const int j8   = lane >> 3;        // 0..7
  const int c8   = lane & 7;         // 16B (4-fp32) index within 32 cols
  const int s_   = c8 >> 1;          // logical 8-col slot
  const int half = c8 & 1;           // 8B half within slot
  const int srow = wave * 32;

#define ISSUE(SET, TC) do {                                                  \
    const float* bp = x + ((size_t)blockIdx.x + (size_t)((TC) >> 3) * 256)   \
                          * (NT * ND) + ((TC) & 7) * 32;                     \
    _Pragma("unroll")                                                        \
    for (int i = 0; i < 4; ++i)                                              \
      SET[i] = *(const f32x4*)(bp + (srow + i * 8 + j8) * ND + c8 * 4);      \
  } while (0)

#define CAST_WRITE(BUF, SET) do {                                            \
    _Pragma("unroll")                                                        \
    for (int i = 0; i < 4; ++i) {                                            \
      const int r = srow + i * 8 + j8;                                       \
      const u32x2 o = pack_bf16x4(SET[i]);                                   \
      const int slot16 = ((r & 1) * 4 + s_) ^ ((r >> 1) & 7);                \
      *(u32x2*)((unsigned int*)&ck[BUF][0]                                   \
                + ((r >> 1) * 32 + slot16 * 4 + half * 2)) = o;              \
    }                                                                        \
  } while (0)

#define MFMA_CHUNK(BUF) do {                                                 \
    const u32x4* cb = &ck[BUF][0];                                           \
    _Pragma("unroll")                                                        \
    for (int kb = 0; kb < 2; ++kb) {                                         \
      const int ko = (sx4 + kb * 2 + hi) ^ sxd;                              \
      bf16x8 fa0  = __builtin_bit_cast(bf16x8, cb[iA  + ko]);                \
      bf16x8 fa1  = __builtin_bit_cast(bf16x8, cb[iA  + 128 + ko]);          \
      bf16x8 fbA0 = __builtin_bit_cast(bf16x8, cb[iBA + ko]);                \
      bf16x8 fbA1 = __builtin_bit_cast(bf16x8, cb[iBA + 128 + ko]);          \
      bf16x8 fbB0 = __builtin_bit_cast(bf16x8, cb[iBB + ko]);                \
      bf16x8 fbB1 = __builtin_bit_cast(bf16x8, cb[iBB + 128 + ko]);          \
      aA0 = MFMA32(fa0, fbA0, aA0, 0, 0, 0);                                 \
      aA1 = MFMA32(fa0, fbA1, aA1, 0, 0, 0);                                 \
      aA2 = MFMA32(fa1, fbA0, aA2, 0, 0, 0);                                 \
      aA3 = MFMA32(fa1, fbA1, aA3, 0, 0, 0);                                 \
      aB0 = MFMA32(fa0, fbB0, aB0, 0, 0, 0);                                 \
      aB1 = MFMA32(fa0, fbB1, aB1, 0, 0, 0);                                 \
      aB2 = MFMA32(fa1, fbB0, aB2, 0, 0, 0);                                 \
      aB3 = MFMA32(fa1, fbB1, aB3, 0, 0, 0);                                 \
    }                                                                        \
  } while (0)

  f32x16 aA0, aA1, aA2, aA3, aB0, aB1, aB2, aB3;
#pragma unroll
  for (int e = 0; e < 16; ++e) {
    aA0[e] = 0.f; aA1[e] = 0.f; aA2[e] = 0.f; aA3[e] = 0.f;
    aB0[e] = 0.f; aB1[e] = 0.f; aB2[e] = 0.f; aB3[e] = 0.f;
  }

  f32x4 ldA[4], ldB[4];
  ISSUE(ldA, 0);
  ISSUE(ldB, 1);

#pragma unroll 1
  for (int g = 0; g < 16; g += 2) {
    // ---- even sub-chunk g: consume ldA, buf0 ----
    CAST_WRITE(0, ldA);
    if (g + 2 < 16) ISSUE(ldA, g + 2);   // lands ~2 sub-chunk periods later
    wg_barrier();
    MFMA_CHUNK(0);

    // ---- odd sub-chunk g+1: consume ldB, buf1 ----
    CAST_WRITE(1, ldB);
    if (g + 3 < 16) ISSUE(ldB, g + 3);
    wg_barrier();
    MFMA_CHUNK(1);

    // ---- batch epilogue at g+1 == 7 (batch 0) and 15 (batch 1) ----
    if (((g + 1) & 7) == 7) {
      const int bb = (int)blockIdx.x + ((g + 1) >> 3) * 256;

      // diagonal tiles (waves 0-3, tile A): publish inv = rsqrt(diag)
      if (d == 0) {
        float dv0 = 1.0f, dv1 = 1.0f;
#pragma unroll
        for (int rg = 0; rg < 16; ++rg) {
          const int rowe = (rg & 3) + 8 * (rg >> 2) + 4 * hi;
          if (rowe == lo5) { dv0 = aA0[rg]; dv1 = aA3[rg]; }
        }
        if (hi == ((lo5 >> 2) & 1)) {
          invbuf[R + lo5]      = rsqrtf(fmaxf(dv0, 1e-24f));
          invbuf[R + 32 + lo5] = rsqrtf(fmaxf(dv1, 1e-24f));
        }
      }
      wg_barrier();   // invbuf valid; next-batch prefetch stays in flight

      // scaled exp column-sums (S symmetric: row-LSE sum == column sum)
      {
        const float ic0 = invbuf[CA + lo5] * K10L2E;
        const float ic1 = invbuf[CA + 32 + lo5] * K10L2E;
        float e0 = 0.f, e1 = 0.f;
#pragma unroll
        for (int rg = 0; rg < 16; ++rg) {
          const int rowe = (rg & 3) + 8 * (rg >> 2) + 4 * hi;
          const float ir0 = invbuf[R + rowe], ir1 = invbuf[R + 32 + rowe];
          e0 += exp2f(fmaf(aA0[rg] * ir0, ic0, -K10L2E));
          e0 += exp2f(fmaf(aA2[rg] * ir1, ic0, -K10L2E));
          e1 += exp2f(fmaf(aA1[rg] * ir0, ic1, -K10L2E));
          e1 += exp2f(fmaf(aA3[rg] * ir1, ic1, -K10L2E));
        }
        e0 += __shfl_xor(e0, 32);
        e1 += __shfl_xor(e1, 32);
        if (hi == 0) sbuf[CA + lo5][tr] = e0;
        else         sbuf[CA + 32 + lo5][tr] = e1;
      }
      {
        const float ic0 = invbuf[CB + lo5] * K10L2E;
        const float ic1 = invbuf[CB + 32 + lo5] * K10L2E;
        float e0 = 0.f, e1 = 0.f;
#pragma unroll
        for (int rg = 0; rg < 16; ++rg) {
          const int rowe = (rg & 3) + 8 * (rg >> 2) + 4 * hi;
          const float ir0 = invbuf[R + rowe], ir1 = invbuf[R + 32 + rowe];
          e0 += exp2f(fmaf(aB0[rg] * ir0, ic0, -K10L2E));
          e0 += exp2f(fmaf(aB2[rg] * ir1, ic0, -K10L2E));
          e1 += exp2f(fmaf(aB1[rg] * ir0, ic1, -K10L2E));
          e1 += exp2f(fmaf(aB3[rg] * ir1, ic1, -K10L2E));
        }
        e0 += __shfl_xor(e0, 32);
        e1 += __shfl_xor(e1, 32);
        if (hi == 0) sbuf[CB + lo5][tr] = e0;
        else         sbuf[CB + 32 + lo5][tr] = e1;
      }

      // super-diagonal target (tiles with tcA==tr or tcA==tr+1)
      if (tcA == tr || tcA == tr + 1) {
#pragma unroll
        for (int ar = 0; ar < 2; ++ar) {
#pragma unroll
          for (int rg = 0; rg < 16; ++rg) {
            const int r = R + ar * 32 + (rg & 3) + 8 * (rg >> 2) + 4 * hi;
            const int tcol = r + 1 - CA;
            if (r < NT - 1 && tcol >= 0 && tcol < 64 && lo5 == (tcol & 31)) {
              const float v = (tcol < 32) ? (ar ? aA2[rg] : aA0[rg])
                                          : (ar ? aA3[rg] : aA1[rg]);
              tbuf[r] = 10.0f * v * invbuf[r] * invbuf[r + 1];
            }
          }
        }
      }
      wg_barrier();   // sbuf/tbuf complete

      // merge 4 row-groups per column, subtract target, block-reduce
      float val = 0.0f;
      if (t < NT - 1) {
        const float s = sbuf[t][0] + sbuf[t][1] + sbuf[t][2] + sbuf[t][3];
        val = 10.0f + __logf(s) - tbuf[t];
      }
#pragma unroll
      for (int dd = 1; dd < 64; dd <<= 1) val += __shfl_xor(val, dd);
      if (lane == 0) redbuf[wave] = val;
      wg_barrier();
      if (t == 0) {
        float s = 0.f;
#pragma unroll
        for (int w = 0; w < 8; ++w) s += redbuf[w];
        atomicExch(&partial[bb], s);   // device-scope store (cross-XCD safe)
      }

      // reset accumulators for next batch
#pragma unroll
      for (int e = 0; e < 16; ++e) {
        aA0[e] = 0.f; aA1[e] = 0.f; aA2[e] = 0.f; aA3[e] = 0.f;
        aB0[e] = 0.f; aB1[e] = 0.f; aB2[e] = 0.f; aB3[e] = 0.f;
      }
    }
  }
#undef ISSUE
#undef CAST_WRITE
#undef MFMA_CHUNK

  // ---- last-block final reduction (replaces separate K3 dispatch) --------
  if (t == 0) {
    __threadfence();                               // partials visible device-wide
    doneflag = (atomicAdd(counter, 1u) == 255u) ? 1u : 0u;
  }
  __syncthreads();
  if (doneflag) {
    float v = 0.0f;
    if (t < 256)                                   // 512 partials, 256 lanes
      v = atomicAdd(&partial[t], 0.0f)             // coherent reads, fixed order
        + atomicAdd(&partial[t + 256], 0.0f);
#pragma unroll
    for (int dd = 1; dd < 64; dd <<= 1) v += __shfl_xor(v, dd);
    if (lane == 0) redbuf[wave] = v;
    __syncthreads();
    if (t == 0) {
      float s2 = 0.f;
#pragma unroll
      for (int w = 0; w < 8; ++w) s2 += redbuf[w];
      out[0] = s2 * (1.0f / (float)(NB * (NT - 1)));
    }
  }
}

extern "C" void kernel_launch(void* const* d_in, const int* in_sizes, int n_in,
                              void* d_out, int out_size, void* d_ws, size_t ws_size,
                              hipStream_t stream) {
  (void)in_sizes; (void)n_in; (void)out_size; (void)ws_size;
  const float* x = (const float*)d_in[0];
  float* out = (float*)d_out;
  float* partial = (float*)d_ws;                                   // 512 floats
  unsigned int* counter = (unsigned int*)((char*)d_ws + NB * sizeof(float));

  hipMemsetAsync(counter, 0, sizeof(unsigned int), stream);        // graph-safe
  hipLaunchKernelGGL(fused_kernel, dim3(NB / 2), dim3(512), 0, stream,
                     x, partial, counter, out);
}

// Round 17
// 38.495 us; speedup vs baseline: 1.2657x; 1.1861x over previous
//
#include <hip/hip_runtime.h>

// TemporalContrastiveLoss: B=512, T=256, D=256, temperature 0.1.
// Grid = 256 blocks (1/CU, 512 thr, launch_bounds(512,2)). 2 batches/block.
// S_raw = X*X^T over 16 sub-chunks (32 cols, 2 batches x 8), depth-2
// register prefetch (ldA[4]/ldB[4], 32 VGPR -- proven no-spill, r9=38.7us).
// lgkm-only barriers (vmcnt never drained in-loop). Symmetric column-sum
// LSE (fixed max=10), super-diagonal target. K3: 512->1 mean.
// r17 change (single variable vs r9): fp32->bf16 cast via native __bf16
// conversions (HW v_cvt_pk_bf16_f32) instead of 5-op bit-twiddle RNE --
// cuts ~8us/block of cast VALU if on critical path. Both are RNE.

typedef float f32x4  __attribute__((ext_vector_type(4)));
typedef float f32x16 __attribute__((ext_vector_type(16)));
typedef unsigned int u32x2 __attribute__((ext_vector_type(2)));
typedef unsigned int u32x4 __attribute__((ext_vector_type(4)));
typedef __bf16 bf16x4 __attribute__((ext_vector_type(4)));
typedef __bf16 bf16x8 __attribute__((ext_vector_type(8)));

#define NB 512
#define NT 256
#define ND 256
#define K10L2E 14.42695041f   // 10 * log2(e)

#define MFMA32 __builtin_amdgcn_mfma_f32_32x32x16_bf16

// Barrier that does NOT drain vmcnt (prefetch stays in flight).
__device__ __forceinline__ void wg_barrier() {
  asm volatile("s_waitcnt lgkmcnt(0)" ::: "memory");
  __builtin_amdgcn_s_barrier();
  asm volatile("" ::: "memory");
}

// Native RNE casts -> compiler emits v_cvt_pk_bf16_f32 pairs (m240: let
// the compiler handle it; bf16 ext-vector IS trivially copyable).
__device__ __forceinline__ u32x2 pack_bf16x4(f32x4 v) {
  bf16x4 b;
  b[0] = (__bf16)v.x; b[1] = (__bf16)v.y;
  b[2] = (__bf16)v.z; b[3] = (__bf16)v.w;
  return __builtin_bit_cast(u32x2, b);
}

// LDS sub-chunk layout (32 cols, 16 KiB): [128 double-rows][8 slot16 of 16B],
// row r, logical 8-col slot s: slot16 = ((r&1)*4 + s) ^ ((r>>1)&7)
// -> ds_read_b128 frags and ds_write_b64 staging both <=2-way (free).
__global__ __launch_bounds__(512, 2) void fused_kernel(
    const float* __restrict__ x, float* __restrict__ partial) {
  __shared__ u32x4 ck[2][128 * 8];   // 2 x 16 KiB sub-chunk double buffer
  __shared__ float invbuf[NT];       // 1/||x_r|| from MFMA diagonal
  __shared__ float sbuf[NT][5];      // per-col, per-64row-group sum exp(p-10)
  __shared__ float tbuf[NT];         // per-row target logit (x10, normalized)
  __shared__ float redbuf[8];

  const int t    = threadIdx.x;
  const int wave = t >> 6;
  const int lane = t & 63;
  const int lo5  = lane & 31;
  const int hi   = lane >> 5;
  const int sxd  = (lo5 >> 1) & 7;   // frag-read row-derived xor
  const int sx4  = (lo5 & 1) * 4;

  // tile assignment: wave w -> tiles (tr, tcA), (tr, tcB); w<4 has diag in A
  const int d   = wave >> 2;
  const int tr  = wave & 3;
  const int tcA = (tr + d) & 3;
  const int tcB = (tr + d + 2) & 3;
  const int R = tr * 64, CA = tcA * 64, CB = tcB * 64;

  // frag base indices (u32x4 units): rows group+lo5; +32 rows => +128
  const int iA  = ((R  + lo5) >> 1) * 8;
  const int iBA = ((CA + lo5) >> 1) * 8;
  const int iBB = ((CB + lo5) >> 1) * 8;

  // staging: wave stages rows wave*32..+31 of each 32-col sub-chunk
  const int j8   = lane >> 3;        // 0..7
  const int c8   = lane & 7;         // 16B (4-fp32) index within 32 cols
  const int s_   = c8 >> 1;          // logical 8-col slot
  const int half = c8 & 1;           // 8B half within slot
  const int srow = wave * 32;

#define ISSUE(SET, TC) do {                                                  \
    const float* bp = x + ((size_t)blockIdx.x + (size_t)((TC) >> 3) * 256)   \
                          * (NT * ND) + ((TC) & 7) * 32;                     \
    _Pragma("unroll")                                                        \
    for (int i = 0; i < 4; ++i)                                              \
      SET[i] = *(const f32x4*)(bp + (srow + i * 8 + j8) * ND + c8 * 4);      \
  } while (0)

#define CAST_WRITE(BUF, SET) do {                                            \
    _Pragma("unroll")                                                        \
    for (int i = 0; i < 4; ++i) {                                            \
      const int r = srow + i * 8 + j8;                                       \
      const u32x2 o = pack_bf16x4(SET[i]);                                   \
      const int slot16 = ((r & 1) * 4 + s_) ^ ((r >> 1) & 7);                \
      *(u32x2*)((unsigned int*)&ck[BUF][0]                                   \
                + ((r >> 1) * 32 + slot16 * 4 + half * 2)) = o;              \
    }                                                                        \
  } while (0)

#define MFMA_CHUNK(BUF) do {                                                 \
    const u32x4* cb = &ck[BUF][0];                                           \
    _Pragma("unroll")                                                        \
    for (int kb = 0; kb < 2; ++kb) {                                         \
      const int ko = (sx4 + kb * 2 + hi) ^ sxd;                              \
      bf16x8 fa0  = __builtin_bit_cast(bf16x8, cb[iA  + ko]);                \
      bf16x8 fa1  = __builtin_bit_cast(bf16x8, cb[iA  + 128 + ko]);          \
      bf16x8 fbA0 = __builtin_bit_cast(bf16x8, cb[iBA + ko]);                \
      bf16x8 fbA1 = __builtin_bit_cast(bf16x8, cb[iBA + 128 + ko]);          \
      bf16x8 fbB0 = __builtin_bit_cast(bf16x8, cb[iBB + ko]);                \
      bf16x8 fbB1 = __builtin_bit_cast(bf16x8, cb[iBB + 128 + ko]);          \
      aA0 = MFMA32(fa0, fbA0, aA0, 0, 0, 0);                                 \
      aA1 = MFMA32(fa0, fbA1, aA1, 0, 0, 0);                                 \
      aA2 = MFMA32(fa1, fbA0, aA2, 0, 0, 0);                                 \
      aA3 = MFMA32(fa1, fbA1, aA3, 0, 0, 0);                                 \
      aB0 = MFMA32(fa0, fbB0, aB0, 0, 0, 0);                                 \
      aB1 = MFMA32(fa0, fbB1, aB1, 0, 0, 0);                                 \
      aB2 = MFMA32(fa1, fbB0, aB2, 0, 0, 0);                                 \
      aB3 = MFMA32(fa1, fbB1, aB3, 0, 0, 0);                                 \
    }                                                                        \
  } while (0)

  f32x16 aA0, aA1, aA2, aA3, aB0, aB1, aB2, aB3;
#pragma unroll
  for (int e = 0; e < 16; ++e) {
    aA0[e] = 0.f; aA1[e] = 0.f; aA2[e] = 0.f; aA3[e] = 0.f;
    aB0[e] = 0.f; aB1[e] = 0.f; aB2[e] = 0.f; aB3[e] = 0.f;
  }

  f32x4 ldA[4], ldB[4];
  ISSUE(ldA, 0);
  ISSUE(ldB, 1);

#pragma unroll 1
  for (int g = 0; g < 16; g += 2) {
    // ---- even sub-chunk g: consume ldA, buf0 ----
    CAST_WRITE(0, ldA);
    if (g + 2 < 16) ISSUE(ldA, g + 2);   // lands ~2 sub-chunk periods later
    wg_barrier();
    MFMA_CHUNK(0);

    // ---- odd sub-chunk g+1: consume ldB, buf1 ----
    CAST_WRITE(1, ldB);
    if (g + 3 < 16) ISSUE(ldB, g + 3);
    wg_barrier();
    MFMA_CHUNK(1);

    // ---- batch epilogue at g+1 == 7 (batch 0) and 15 (batch 1) ----
    if (((g + 1) & 7) == 7) {
      const int bb = (int)blockIdx.x + ((g + 1) >> 3) * 256;

      // diagonal tiles (waves 0-3, tile A): publish inv = rsqrt(diag)
      if (d == 0) {
        float dv0 = 1.0f, dv1 = 1.0f;
#pragma unroll
        for (int rg = 0; rg < 16; ++rg) {
          const int rowe = (rg & 3) + 8 * (rg >> 2) + 4 * hi;
          if (rowe == lo5) { dv0 = aA0[rg]; dv1 = aA3[rg]; }
        }
        if (hi == ((lo5 >> 2) & 1)) {
          invbuf[R + lo5]      = rsqrtf(fmaxf(dv0, 1e-24f));
          invbuf[R + 32 + lo5] = rsqrtf(fmaxf(dv1, 1e-24f));
        }
      }
      wg_barrier();   // invbuf valid; next-batch prefetch stays in flight

      // scaled exp column-sums (S symmetric: row-LSE sum == column sum)
      {
        const float ic0 = invbuf[CA + lo5] * K10L2E;
        const float ic1 = invbuf[CA + 32 + lo5] * K10L2E;
        float e0 = 0.f, e1 = 0.f;
#pragma unroll
        for (int rg = 0; rg < 16; ++rg) {
          const int rowe = (rg & 3) + 8 * (rg >> 2) + 4 * hi;
          const float ir0 = invbuf[R + rowe], ir1 = invbuf[R + 32 + rowe];
          e0 += exp2f(fmaf(aA0[rg] * ir0, ic0, -K10L2E));
          e0 += exp2f(fmaf(aA2[rg] * ir1, ic0, -K10L2E));
          e1 += exp2f(fmaf(aA1[rg] * ir0, ic1, -K10L2E));
          e1 += exp2f(fmaf(aA3[rg] * ir1, ic1, -K10L2E));
        }
        e0 += __shfl_xor(e0, 32);
        e1 += __shfl_xor(e1, 32);
        if (hi == 0) sbuf[CA + lo5][tr] = e0;
        else         sbuf[CA + 32 + lo5][tr] = e1;
      }
      {
        const float ic0 = invbuf[CB + lo5] * K10L2E;
        const float ic1 = invbuf[CB + 32 + lo5] * K10L2E;
        float e0 = 0.f, e1 = 0.f;
#pragma unroll
        for (int rg = 0; rg < 16; ++rg) {
          const int rowe = (rg & 3) + 8 * (rg >> 2) + 4 * hi;
          const float ir0 = invbuf[R + rowe], ir1 = invbuf[R + 32 + rowe];
          e0 += exp2f(fmaf(aB0[rg] * ir0, ic0, -K10L2E));
          e0 += exp2f(fmaf(aB2[rg] * ir1, ic0, -K10L2E));
          e1 += exp2f(fmaf(aB1[rg] * ir0, ic1, -K10L2E));
          e1 += exp2f(fmaf(aB3[rg] * ir1, ic1, -K10L2E));
        }
        e0 += __shfl_xor(e0, 32);
        e1 += __shfl_xor(e1, 32);
        if (hi == 0) sbuf[CB + lo5][tr] = e0;
        else         sbuf[CB + 32 + lo5][tr] = e1;
      }

      // super-diagonal target (tiles with tcA==tr or tcA==tr+1)
      if (tcA == tr || tcA == tr + 1) {
#pragma unroll
        for (int ar = 0; ar < 2; ++ar) {
#pragma unroll
          for (int rg = 0; rg < 16; ++rg) {
            const int r = R + ar * 32 + (rg & 3) + 8 * (rg >> 2) + 4 * hi;
            const int tcol = r + 1 - CA;
            if (r < NT - 1 && tcol >= 0 && tcol < 64 && lo5 == (tcol & 31)) {
              const float v = (tcol < 32) ? (ar ? aA2[rg] : aA0[rg])
                                          : (ar ? aA3[rg] : aA1[rg]);
              tbuf[r] = 10.0f * v * invbuf[r] * invbuf[r + 1];
            }
          }
        }
      }
      wg_barrier();   // sbuf/tbuf complete

      // merge 4 row-groups per column, subtract target, block-reduce
      float val = 0.0f;
      if (t < NT - 1) {
        const float s = sbuf[t][0] + sbuf[t][1] + sbuf[t][2] + sbuf[t][3];
        val = 10.0f + __logf(s) - tbuf[t];
      }
#pragma unroll
      for (int dd = 1; dd < 64; dd <<= 1) val += __shfl_xor(val, dd);
      if (lane == 0) redbuf[wave] = val;
      wg_barrier();
      if (t == 0) {
        float s = 0.f;
#pragma unroll
        for (int w = 0; w < 8; ++w) s += redbuf[w];
        partial[bb] = s;
      }

      // reset accumulators for next batch
#pragma unroll
      for (int e = 0; e < 16; ++e) {
        aA0[e] = 0.f; aA1[e] = 0.f; aA2[e] = 0.f; aA3[e] = 0.f;
        aB0[e] = 0.f; aB1[e] = 0.f; aB2[e] = 0.f; aB3[e] = 0.f;
      }
    }
  }
#undef ISSUE
#undef CAST_WRITE
#undef MFMA_CHUNK
}

// ---------------- K3: 512 partials -> mean (deterministic) ----------------
__global__ __launch_bounds__(256) void reduce_kernel(
    const float* __restrict__ partial, float* __restrict__ out) {
  const int t = threadIdx.x;
  float v = partial[t] + partial[t + 256];
#pragma unroll
  for (int d = 1; d < 64; d <<= 1) v += __shfl_xor(v, d);
  __shared__ float red[4];
  if ((t & 63) == 0) red[t >> 6] = v;
  __syncthreads();
  if (t == 0)
    out[0] = (red[0] + red[1] + red[2] + red[3]) * (1.0f / (float)(NB * (NT - 1)));
}

extern "C" void kernel_launch(void* const* d_in, const int* in_sizes, int n_in,
                              void* d_out, int out_size, void* d_ws, size_t ws_size,
                              hipStream_t stream) {
  (void)in_sizes; (void)n_in; (void)out_size; (void)ws_size;
  const float* x = (const float*)d_in[0];
  float* out = (float*)d_out;
  float* partial = (float*)d_ws;   // 2 KiB

  hipLaunchKernelGGL(fused_kernel, dim3(NB / 2), dim3(512), 0, stream, x, partial);
  hipLaunchKernelGGL(reduce_kernel, dim3(1), dim3(256), 0, stream, partial, out);
}